// Round 1
// baseline (126.058 us; speedup 1.0000x reference)
//
#include <hip/hip_runtime.h>

#define B_DIM 64
#define N_DIM 16384
#define TOTAL (B_DIM * N_DIM)

__device__ __forceinline__ float sigmoidf_(float x) {
    return 1.0f / (1.0f + __expf(-x));
}

// ---------------- global max of criticality -> ws[0] (as uint bits) ----------
__global__ __launch_bounds__(256) void crit_max_kernel(
        const float* __restrict__ crit, unsigned int* __restrict__ ws, int n4) {
    int idx = blockIdx.x * blockDim.x + threadIdx.x;
    float m = 0.0f;
    const float4* c4 = (const float4*)crit;
    for (int i = idx; i < n4; i += gridDim.x * blockDim.x) {
        float4 v = c4[i];
        m = fmaxf(fmaxf(m, v.x), fmaxf(fmaxf(v.y, v.z), v.w));
    }
#pragma unroll
    for (int off = 32; off > 0; off >>= 1)
        m = fmaxf(m, __shfl_xor(m, off));
    if ((threadIdx.x & 63) == 0)
        atomicMax(ws, __float_as_uint(m));
}

// ---------------- fused risk kernel -----------------------------------------
__global__ __launch_bounds__(256) void risk_kernel(
        const float* __restrict__ tp,   const float* __restrict__ crit,
        const float* __restrict__ conn, const float* __restrict__ sens,
        const float* __restrict__ bv,   const float* __restrict__ dsv,
        const float* __restrict__ comp, const float* __restrict__ rt,
        const float* __restrict__ sev,
        const float* __restrict__ ctxW1, const float* __restrict__ ctxb1,
        const float* __restrict__ ctxW2, const float* __restrict__ ctxb2,
        const float* __restrict__ ctxW3, const float* __restrict__ ctxb3,
        const float* __restrict__ pW1,  const float* __restrict__ pb1,
        const float* __restrict__ pW2,  const float* __restrict__ pb2,
        const float* __restrict__ pW3,  const float* __restrict__ pb3,
        const float* __restrict__ pWo,  const float* __restrict__ pbo,
        const float* __restrict__ w_threat, const float* __restrict__ w_impact,
        const float* __restrict__ w_vuln,   const float* __restrict__ w_ctx,
        const unsigned int* __restrict__ ws_max,
        float* __restrict__ out, int n) {
    int i = blockIdx.x * blockDim.x + threadIdx.x;
    if (i >= n) return;

    // uniform scalars
    float m   = __uint_as_float(ws_max[0]);
    float wt  = w_threat[0], wi = w_impact[0], wv = w_vuln[0], wc = w_ctx[0];
    float tw  = wt + wi + wv + wc;
    float mden = fmaxf(m, 1e-12f);

    // --- risk components ---
    float threat = sigmoidf_(3.0f * tp[i]);
    float c      = crit[i];
    float impact = (m > 0.0f) ? (c / mden) : c;
    float vuln   = sev[i] * 0.1f;

    // --- ContextEncoder: 4 -> 16 -> 8 -> 1 ---
    float c0 = bv[i], c1 = dsv[i], c2 = comp[i];
    float c3 = 1.0f / (rt[i] + 1e-6f);

    float h1[16];
#pragma unroll
    for (int j = 0; j < 16; ++j) {
        float a = ctxb1[j];
        a = fmaf(c0, ctxW1[j], a);
        a = fmaf(c1, ctxW1[16 + j], a);
        a = fmaf(c2, ctxW1[32 + j], a);
        a = fmaf(c3, ctxW1[48 + j], a);
        h1[j] = fmaxf(a, 0.0f);
    }
    float h2[8];
#pragma unroll
    for (int k = 0; k < 8; ++k) h2[k] = ctxb2[k];
#pragma unroll
    for (int j = 0; j < 16; ++j) {
#pragma unroll
        for (int k = 0; k < 8; ++k)
            h2[k] = fmaf(h1[j], ctxW2[j * 8 + k], h2[k]);
    }
    float a3 = ctxb3[0];
#pragma unroll
    for (int k = 0; k < 8; ++k)
        a3 = fmaf(fmaxf(h2[k], 0.0f), ctxW3[k], a3);
    float ctxr = sigmoidf_(a3);

    // --- weighted combination ---
    float base = (wt * threat + wi * impact + wv * vuln + wc * ctxr) / tw;

    // --- RiskPropagationNetwork: 4 -> 64 -> 32 -> 16 -> 1 ---
    float g0 = base, g1 = c, g2 = conn[i], g3 = sens[i];

    float acc2[32];
#pragma unroll
    for (int k = 0; k < 32; ++k) acc2[k] = pb2[k];
    // layer1 hidden unit computed on the fly inside the layer2 loop
    for (int j = 0; j < 64; ++j) {
        float h = pb1[j];
        h = fmaf(g0, pW1[j], h);
        h = fmaf(g1, pW1[64 + j], h);
        h = fmaf(g2, pW1[128 + j], h);
        h = fmaf(g3, pW1[192 + j], h);
        h = fmaxf(h, 0.0f);
        const float* w2row = pW2 + j * 32;
#pragma unroll
        for (int k = 0; k < 32; ++k)
            acc2[k] = fmaf(h, w2row[k], acc2[k]);
    }

    float acc3[16];
#pragma unroll
    for (int k = 0; k < 16; ++k) acc3[k] = pb3[k];
    for (int j = 0; j < 32; ++j) {
        float h = fmaxf(acc2[j], 0.0f);
        const float* w3row = pW3 + j * 16;
#pragma unroll
        for (int k = 0; k < 16; ++k)
            acc3[k] = fmaf(h, w3row[k], acc3[k]);
    }

    float ao = pbo[0];
#pragma unroll
    for (int k = 0; k < 16; ++k)
        ao = fmaf(fmaxf(acc3[k], 0.0f), pWo[k], ao);

    out[i] = sigmoidf_(ao);
}

extern "C" void kernel_launch(void* const* d_in, const int* in_sizes, int n_in,
                              void* d_out, int out_size, void* d_ws, size_t ws_size,
                              hipStream_t stream) {
    const float* tp    = (const float*)d_in[0];
    const float* crit  = (const float*)d_in[1];
    const float* conn  = (const float*)d_in[2];
    const float* sens  = (const float*)d_in[3];
    const float* bv    = (const float*)d_in[4];
    const float* dsv   = (const float*)d_in[5];
    const float* comp  = (const float*)d_in[6];
    const float* rt    = (const float*)d_in[7];
    const float* sev   = (const float*)d_in[8];
    const float* ctxW1 = (const float*)d_in[9];
    const float* ctxb1 = (const float*)d_in[10];
    const float* ctxW2 = (const float*)d_in[11];
    const float* ctxb2 = (const float*)d_in[12];
    const float* ctxW3 = (const float*)d_in[13];
    const float* ctxb3 = (const float*)d_in[14];
    const float* pW1   = (const float*)d_in[15];
    const float* pb1   = (const float*)d_in[16];
    const float* pW2   = (const float*)d_in[17];
    const float* pb2   = (const float*)d_in[18];
    const float* pW3   = (const float*)d_in[19];
    const float* pb3   = (const float*)d_in[20];
    const float* pWo   = (const float*)d_in[21];
    const float* pbo   = (const float*)d_in[22];
    const float* w_t   = (const float*)d_in[23];
    const float* w_i   = (const float*)d_in[24];
    const float* w_v   = (const float*)d_in[25];
    const float* w_c   = (const float*)d_in[26];

    unsigned int* ws_max = (unsigned int*)d_ws;
    float* out = (float*)d_out;

    // init max accumulator (criticality >= 0, so 0 bits == -0.0f works as identity)
    hipMemsetAsync(ws_max, 0, sizeof(unsigned int), stream);

    // global max of criticality
    int n4 = TOTAL / 4;
    crit_max_kernel<<<1024, 256, 0, stream>>>(crit, ws_max, n4);

    // fused main kernel
    int blocks = (TOTAL + 255) / 256;
    risk_kernel<<<blocks, 256, 0, stream>>>(
        tp, crit, conn, sens, bv, dsv, comp, rt, sev,
        ctxW1, ctxb1, ctxW2, ctxb2, ctxW3, ctxb3,
        pW1, pb1, pW2, pb2, pW3, pb3, pWo, pbo,
        w_t, w_i, w_v, w_c, ws_max, out, TOTAL);
}

// Round 2
// 95.054 us; speedup vs baseline: 1.3262x; 1.3262x over previous
//
#include <hip/hip_runtime.h>

typedef short bf16x8 __attribute__((ext_vector_type(8)));
typedef float f32x4 __attribute__((ext_vector_type(4)));
typedef unsigned int uint;

#define TOTAL (64 * 16384)
#define ITERS 2
#define BLOCKS (TOTAL / (256 * ITERS)) // 2048

__device__ __forceinline__ uint bf16rne(float x) {
    uint b = __float_as_uint(x);
    return (b + 0x7fffu + ((b >> 16) & 1u)) >> 16;
}
__device__ __forceinline__ short bf16s(float x) { return (short)bf16rne(x); }
__device__ __forceinline__ float relu_(float x) { return fmaxf(x, 0.0f); }
__device__ __forceinline__ float fast_sigmoid(float x) {
    return __builtin_amdgcn_rcpf(1.0f + __expf(-x));
}

// ---------------- global max of criticality -> ws[0] (as uint bits) ----------
__global__ __launch_bounds__(256) void crit_max_kernel(
        const float* __restrict__ crit, unsigned int* __restrict__ ws, int n4) {
    int idx = blockIdx.x * blockDim.x + threadIdx.x;
    float m = 0.0f;
    const float4* c4 = (const float4*)crit;
    for (int i = idx; i < n4; i += gridDim.x * blockDim.x) {
        float4 v = c4[i];
        m = fmaxf(fmaxf(m, v.x), fmaxf(fmaxf(v.y, v.z), v.w));
    }
#pragma unroll
    for (int off = 32; off > 0; off >>= 1)
        m = fmaxf(m, __shfl_xor(m, off));
    if ((threadIdx.x & 63) == 0)
        atomicMax(ws, __float_as_uint(m));
}

// ---------------- fused MFMA risk kernel ------------------------------------
__global__ __launch_bounds__(256, 2) void risk_mfma_kernel(
        const float* __restrict__ tp,   const float* __restrict__ crit,
        const float* __restrict__ conn, const float* __restrict__ sens,
        const float* __restrict__ bv,   const float* __restrict__ dsv,
        const float* __restrict__ comp, const float* __restrict__ rt,
        const float* __restrict__ sev,
        const float* __restrict__ ctxW1, const float* __restrict__ ctxb1,
        const float* __restrict__ ctxW2, const float* __restrict__ ctxb2,
        const float* __restrict__ ctxW3, const float* __restrict__ ctxb3,
        const float* __restrict__ pW1,  const float* __restrict__ pb1,
        const float* __restrict__ pW2,  const float* __restrict__ pb2,
        const float* __restrict__ pW3,  const float* __restrict__ pb3,
        const float* __restrict__ pWo,  const float* __restrict__ pbo,
        const float* __restrict__ w_threat, const float* __restrict__ w_impact,
        const float* __restrict__ w_vuln,   const float* __restrict__ w_ctx,
        const unsigned int* __restrict__ ws_max,
        float* __restrict__ out) {
    const int lane = threadIdx.x & 63;
    const int wid  = threadIdx.x >> 6;
    const int g    = lane >> 4;   // 0..3
    const int c    = lane & 15;   // 0..15

    // per-wave private LDS slab (no cross-wave sharing -> no barriers needed)
    __shared__ uint4 lds4[4][320]; // 5120 B per wave
    char*  my   = (char*)lds4[wid];
    char*  feat = my;              // [64 elems][16 B]  8 bf16 features
    char*  act1 = my + 1024;       // [16 elems][128 B] 64 bf16, chunk^(c&7) swizzle
    char*  act2 = my + 3072;       // [16 elems][64 B]  32 bf16, chunk^(c&3) swizzle
    char*  cact = my + 4096;       // [16 elems][32 B]  16 bf16, chunk^(c&1) swizzle
    float* pbf  = (float*)(my + 4608); // [64] f32 partial base

    const bf16x8 z8 = {0,0,0,0,0,0,0,0};
    const f32x4  z4 = {0.f,0.f,0.f,0.f};

    // ---- uniform scalars ----
    const float m   = __uint_as_float(ws_max[0]);
    const float wt  = w_threat[0], wi = w_impact[0], wv = w_vuln[0], wc = w_ctx[0];
    const float inv_tw = 1.0f / (wt + wi + wv + wc);
    const float inv_md = 1.0f / fmaxf(m, 1e-12f);
    const float wcn = wc * inv_tw;
    const float cb3 = ctxb3[0];
    const float pbo0 = pbo[0];

    // ---- weight fragments (A operand: row = out = lane&15, k = 8*g + i) ----
    // prop W1 (4x64) + b1 folded at k==4 (B supplies 1.0 there)
    bf16x8 w1f[4];
#pragma unroll
    for (int nt = 0; nt < 4; ++nt) {
        bf16x8 f = z8;
        if (g == 0) {
#pragma unroll
            for (int i = 0; i < 4; ++i) f[i] = bf16s(pW1[i * 64 + nt * 16 + c]);
            f[4] = bf16s(pb1[nt * 16 + c]);
        }
        w1f[nt] = f;
    }
    // prop W2 (64x32): 2 N-tiles x 2 K-frags
    bf16x8 w2f[2][2];
#pragma unroll
    for (int nt = 0; nt < 2; ++nt)
#pragma unroll
        for (int kf = 0; kf < 2; ++kf) {
            bf16x8 f;
#pragma unroll
            for (int i = 0; i < 8; ++i) {
                int k = kf * 32 + 8 * g + i;
                f[i] = bf16s(pW2[k * 32 + nt * 16 + c]);
            }
            w2f[nt][kf] = f;
        }
    // prop W3 (32x16)
    bf16x8 w3f;
#pragma unroll
    for (int i = 0; i < 8; ++i) w3f[i] = bf16s(pW3[(8 * g + i) * 16 + c]);
    // ctx W1 (4x16) + ctx_b1 at k==4
    bf16x8 cw1f = z8;
    if (g == 0) {
#pragma unroll
        for (int i = 0; i < 4; ++i) cw1f[i] = bf16s(ctxW1[i * 16 + c]);
        cw1f[4] = bf16s(ctxb1[c]);
    }
    // ctx W2 (16x8), K padded to 32, N padded to 16 with zeros
    bf16x8 cw2f = z8;
    if (g < 2) {
#pragma unroll
        for (int i = 0; i < 8; ++i) {
            int k = 8 * g + i; // < 16
            cw2f[i] = (c < 8) ? bf16s(ctxW2[k * 8 + c]) : (short)0;
        }
    }
    // bias / epilogue vectors (per-lane row group 4g+r)
    f32x4 b2i[2];
#pragma unroll
    for (int nt = 0; nt < 2; ++nt) {
        float4 t = ((const float4*)pb2)[nt * 4 + g];
        b2i[nt] = (f32x4){t.x, t.y, t.z, t.w};
    }
    float4 t3 = ((const float4*)pb3)[g];
    f32x4 b3i = (f32x4){t3.x, t3.y, t3.z, t3.w};
    f32x4 cb2i = z4;
    float4 cw3v = make_float4(0.f, 0.f, 0.f, 0.f);
    if (g < 2) {
        float4 tb = ((const float4*)ctxb2)[g];
        cb2i = (f32x4){tb.x, tb.y, tb.z, tb.w};
        cw3v = ((const float4*)ctxW3)[g];
    }
    float4 wog = ((const float4*)pWo)[g];

    const int eb0 = blockIdx.x * (256 * ITERS);

    for (int it = 0; it < ITERS; ++it) {
        const int ewave = eb0 + it * 256 + wid * 64;
        // ---------------- phase 1: per-element components (64-wide) ----------
        {
            const int e = ewave + lane;
            float tpv = tp[e], cv = crit[e], cnv = conn[e], snv = sens[e];
            float bvv = bv[e], dvv = dsv[e], cpv = comp[e], rtv = rt[e], svv = sev[e];
            float threat = fast_sigmoid(3.0f * tpv);
            float impact = (m > 0.0f) ? cv * inv_md : cv;
            float vuln   = svv * 0.1f;
            float invrt  = __builtin_amdgcn_rcpf(rtv + 1e-6f);
            float pbase  = (wt * threat + wi * impact + wv * vuln) * inv_tw;
            uint4 fv;
            fv.x = bf16rne(bvv) | (bf16rne(dvv) << 16);
            fv.y = bf16rne(cpv) | (bf16rne(invrt) << 16);
            fv.z = 0x3f80u      | (bf16rne(cv) << 16);   // [1.0 | crit]
            fv.w = bf16rne(cnv) | (bf16rne(snv) << 16);  // [conn | sens]
            *(uint4*)(feat + lane * 16) = fv;
            pbf[lane] = pbase;
        }
        // ---------------- phase 2: 4 tiles of 16 elements --------------------
        float ovs[4];
#pragma unroll
        for (int t = 0; t < 4; ++t) {
            // feature row for element t*16+c (only k=0..7 lanes, g==0)
            uint4 fr = make_uint4(0u, 0u, 0u, 0u);
            if (g == 0) fr = *(const uint4*)(feat + (t * 16 + c) * 16);
            bf16x8 bctx = __builtin_bit_cast(bf16x8, fr);
            // ctx L1: 4->16 (+bias via k=4)
            f32x4 cc1 = __builtin_amdgcn_mfma_f32_16x16x32_bf16(cw1f, bctx, z4, 0, 0, 0);
            {
                uint lo = bf16rne(relu_(cc1[0])) | (bf16rne(relu_(cc1[1])) << 16);
                uint hi = bf16rne(relu_(cc1[2])) | (bf16rne(relu_(cc1[3])) << 16);
                *(uint2*)(cact + c * 32 + (((g >> 1) ^ (c & 1)) << 4) + 8 * (g & 1)) =
                    make_uint2(lo, hi);
            }
            // ctx L2: 16->8
            bf16x8 b2c = z8;
            if (g < 2) b2c = *(const bf16x8*)(cact + c * 32 + ((g ^ (c & 1)) << 4));
            f32x4 cc2 = __builtin_amdgcn_mfma_f32_16x16x32_bf16(cw2f, b2c, cb2i, 0, 0, 0);
            float pc = fmaf(relu_(cc2[0]), cw3v.x, fmaf(relu_(cc2[1]), cw3v.y,
                       fmaf(relu_(cc2[2]), cw3v.z, relu_(cc2[3]) * cw3v.w)));
            pc += __shfl_xor(pc, 16);
            pc += __shfl_xor(pc, 32);
            float ctxr = fast_sigmoid(pc + cb3);
            float base = fmaf(wcn, ctxr, pbf[t * 16 + c]);
            // prop L1 B-frag: [base, crit, conn, sens, 1.0, 0,0,0]
            uint4 pfu = make_uint4(0u, 0u, 0u, 0u);
            if (g == 0) {
                pfu.x = bf16rne(base) | (fr.z & 0xffff0000u);
                pfu.y = fr.w;
                pfu.z = 0x3f80u;
            }
            bf16x8 bp = __builtin_bit_cast(bf16x8, pfu);
            // prop L1: 4->64
            f32x4 c1[4];
#pragma unroll
            for (int nt = 0; nt < 4; ++nt)
                c1[nt] = __builtin_amdgcn_mfma_f32_16x16x32_bf16(w1f[nt], bp, z4, 0, 0, 0);
#pragma unroll
            for (int nt = 0; nt < 4; ++nt) {
                uint lo = bf16rne(relu_(c1[nt][0])) | (bf16rne(relu_(c1[nt][1])) << 16);
                uint hi = bf16rne(relu_(c1[nt][2])) | (bf16rne(relu_(c1[nt][3])) << 16);
                *(uint2*)(act1 + c * 128 + (((2 * nt + (g >> 1)) ^ (c & 7)) << 4) + 8 * (g & 1)) =
                    make_uint2(lo, hi);
            }
            // prop L2: 64->32
            bf16x8 a0 = *(const bf16x8*)(act1 + c * 128 + ((g ^ (c & 7)) << 4));
            bf16x8 a1 = *(const bf16x8*)(act1 + c * 128 + (((4 + g) ^ (c & 7)) << 4));
            f32x4 c2[2];
#pragma unroll
            for (int nt = 0; nt < 2; ++nt) {
                f32x4 acc = __builtin_amdgcn_mfma_f32_16x16x32_bf16(w2f[nt][0], a0, b2i[nt], 0, 0, 0);
                c2[nt] = __builtin_amdgcn_mfma_f32_16x16x32_bf16(w2f[nt][1], a1, acc, 0, 0, 0);
            }
#pragma unroll
            for (int nt = 0; nt < 2; ++nt) {
                uint lo = bf16rne(relu_(c2[nt][0])) | (bf16rne(relu_(c2[nt][1])) << 16);
                uint hi = bf16rne(relu_(c2[nt][2])) | (bf16rne(relu_(c2[nt][3])) << 16);
                *(uint2*)(act2 + c * 64 + (((2 * nt + (g >> 1)) ^ (c & 3)) << 4) + 8 * (g & 1)) =
                    make_uint2(lo, hi);
            }
            // prop L3: 32->16
            bf16x8 a3 = *(const bf16x8*)(act2 + c * 64 + ((g ^ (c & 3)) << 4));
            f32x4 c3 = __builtin_amdgcn_mfma_f32_16x16x32_bf16(w3f, a3, b3i, 0, 0, 0);
            // output layer 16->1 + sigmoid (VALU + cross-group reduce)
            float p = fmaf(relu_(c3[0]), wog.x, fmaf(relu_(c3[1]), wog.y,
                      fmaf(relu_(c3[2]), wog.z, relu_(c3[3]) * wog.w)));
            p += __shfl_xor(p, 16);
            p += __shfl_xor(p, 32);
            ovs[t] = fast_sigmoid(p + pbo0);
        }
        // lane (g,c) stores element ewave + g*16 + c == ewave + lane (coalesced)
        float ov = (g == 0) ? ovs[0] : (g == 1) ? ovs[1] : (g == 2) ? ovs[2] : ovs[3];
        out[ewave + lane] = ov;
    }
}

extern "C" void kernel_launch(void* const* d_in, const int* in_sizes, int n_in,
                              void* d_out, int out_size, void* d_ws, size_t ws_size,
                              hipStream_t stream) {
    const float* tp    = (const float*)d_in[0];
    const float* crit  = (const float*)d_in[1];
    const float* conn  = (const float*)d_in[2];
    const float* sens  = (const float*)d_in[3];
    const float* bv    = (const float*)d_in[4];
    const float* dsv   = (const float*)d_in[5];
    const float* comp  = (const float*)d_in[6];
    const float* rt    = (const float*)d_in[7];
    const float* sev   = (const float*)d_in[8];
    const float* ctxW1 = (const float*)d_in[9];
    const float* ctxb1 = (const float*)d_in[10];
    const float* ctxW2 = (const float*)d_in[11];
    const float* ctxb2 = (const float*)d_in[12];
    const float* ctxW3 = (const float*)d_in[13];
    const float* ctxb3 = (const float*)d_in[14];
    const float* pW1   = (const float*)d_in[15];
    const float* pb1   = (const float*)d_in[16];
    const float* pW2   = (const float*)d_in[17];
    const float* pb2   = (const float*)d_in[18];
    const float* pW3   = (const float*)d_in[19];
    const float* pb3   = (const float*)d_in[20];
    const float* pWo   = (const float*)d_in[21];
    const float* pbo   = (const float*)d_in[22];
    const float* w_t   = (const float*)d_in[23];
    const float* w_i   = (const float*)d_in[24];
    const float* w_v   = (const float*)d_in[25];
    const float* w_c   = (const float*)d_in[26];

    unsigned int* ws_max = (unsigned int*)d_ws;
    float* out = (float*)d_out;

    hipMemsetAsync(ws_max, 0, sizeof(unsigned int), stream);
    crit_max_kernel<<<1024, 256, 0, stream>>>(crit, ws_max, TOTAL / 4);
    risk_mfma_kernel<<<BLOCKS, 256, 0, stream>>>(
        tp, crit, conn, sens, bv, dsv, comp, rt, sev,
        ctxW1, ctxb1, ctxW2, ctxb2, ctxW3, ctxb3,
        pW1, pb1, pW2, pb2, pW3, pb3, pWo, pbo,
        w_t, w_i, w_v, w_c, ws_max, out);
}

// Round 4
// 56.425 us; speedup vs baseline: 2.2341x; 1.6846x over previous
//
#include <hip/hip_runtime.h>
#include <hip/hip_bf16.h>

typedef short bf16x8 __attribute__((ext_vector_type(8)));
typedef float f32x4 __attribute__((ext_vector_type(4)));
typedef unsigned int uint;

#define TOTAL (64 * 16384)
#define BLOCKS (TOTAL / 256) // 4096

__device__ __forceinline__ uint bf16rne(float x) {
    uint b = __float_as_uint(x);
    return (b + 0x7fffu + ((b >> 16) & 1u)) >> 16;
}
__device__ __forceinline__ short bf16s(float x) { return (short)bf16rne(x); }
__device__ __forceinline__ uint pk2(float lo, float hi) {
    __hip_bfloat162 h2 = __float22bfloat162_rn(make_float2(lo, hi));
    uint u;
    __builtin_memcpy(&u, &h2, sizeof(u));
    return u;
}
__device__ __forceinline__ float relu_(float x) { return fmaxf(x, 0.0f); }
__device__ __forceinline__ float fast_sigmoid(float x) {
    return __builtin_amdgcn_rcpf(1.0f + __expf(-x));
}

// ---------------- global max of criticality -> ws[0] (as uint bits) ----------
// 256 blocks, one atomic per block (atomic serialization was 49us with 4096)
__global__ __launch_bounds__(256) void crit_max_kernel(
        const float* __restrict__ crit, unsigned int* __restrict__ ws, int n4) {
    __shared__ float smax[4];
    const int tid = threadIdx.x;
    float m = 0.0f;
    const float4* c4 = (const float4*)crit;
    for (int i = blockIdx.x * 256 + tid; i < n4; i += gridDim.x * 256) {
        float4 v = c4[i];
        m = fmaxf(fmaxf(m, v.x), fmaxf(fmaxf(v.y, v.z), v.w));
    }
#pragma unroll
    for (int off = 32; off > 0; off >>= 1)
        m = fmaxf(m, __shfl_xor(m, off));
    if ((tid & 63) == 0) smax[tid >> 6] = m;
    __syncthreads();
    if (tid == 0) {
        m = fmaxf(fmaxf(smax[0], smax[1]), fmaxf(smax[2], smax[3]));
        atomicMax(ws, __float_as_uint(m));
    }
}

// ---------------- fused MFMA risk kernel ------------------------------------
__global__ __launch_bounds__(256, 3) void risk_mfma_kernel(
        const float* __restrict__ tp,   const float* __restrict__ crit,
        const float* __restrict__ conn, const float* __restrict__ sens,
        const float* __restrict__ bv,   const float* __restrict__ dsv,
        const float* __restrict__ comp, const float* __restrict__ rt,
        const float* __restrict__ sev,
        const float* __restrict__ ctxW1, const float* __restrict__ ctxb1,
        const float* __restrict__ ctxW2, const float* __restrict__ ctxb2,
        const float* __restrict__ ctxW3, const float* __restrict__ ctxb3,
        const float* __restrict__ pW1,  const float* __restrict__ pb1,
        const float* __restrict__ pW2,  const float* __restrict__ pb2,
        const float* __restrict__ pW3,  const float* __restrict__ pb3,
        const float* __restrict__ pWo,  const float* __restrict__ pbo,
        const float* __restrict__ w_threat, const float* __restrict__ w_impact,
        const float* __restrict__ w_vuln,   const float* __restrict__ w_ctx,
        const unsigned int* __restrict__ ws_max,
        float* __restrict__ out) {
    const int lane = threadIdx.x & 63;
    const int wid  = threadIdx.x >> 6;
    const int g    = lane >> 4;   // 0..3
    const int c    = lane & 15;   // 0..15

    // per-wave private LDS slab; ping-pong act buffers across tiles (parity)
    // layout per wave: feat[1024] | pbf[256] | slab0[3584] | slab1[3584] = 8448 B
    __shared__ uint4 lds4[4][528];
    char*  my   = (char*)lds4[wid];
    char*  feat = my;                   // [64 elems][16 B] 8 bf16 features
    float* pbf  = (float*)(my + 1024);  // [64] f32 partial base
    // slab(p): act1 = +0 (2048 B), act2 = +2048 (1024 B), cact = +3072 (512 B)

    const bf16x8 z8 = {0,0,0,0,0,0,0,0};
    const f32x4  z4 = {0.f,0.f,0.f,0.f};

    // ---- uniform scalars ----
    const float m   = __uint_as_float(ws_max[0]);
    const float wt  = w_threat[0], wi = w_impact[0], wv = w_vuln[0], wc = w_ctx[0];
    const float inv_tw = 1.0f / (wt + wi + wv + wc);
    const float inv_md = 1.0f / fmaxf(m, 1e-12f);
    const float wcn = wc * inv_tw;
    const float cb3 = ctxb3[0];
    const float pbo0 = pbo[0];

    // ---- weight fragments (A operand: row = out = lane&15, k = 8*g + i) ----
    bf16x8 w1f[4];
#pragma unroll
    for (int nt = 0; nt < 4; ++nt) {
        bf16x8 f = z8;
        if (g == 0) {
#pragma unroll
            for (int i = 0; i < 4; ++i) f[i] = bf16s(pW1[i * 64 + nt * 16 + c]);
            f[4] = bf16s(pb1[nt * 16 + c]);
        }
        w1f[nt] = f;
    }
    bf16x8 w2f[2][2];
#pragma unroll
    for (int nt = 0; nt < 2; ++nt)
#pragma unroll
        for (int kf = 0; kf < 2; ++kf) {
            bf16x8 f;
#pragma unroll
            for (int i = 0; i < 8; ++i) {
                int k = kf * 32 + 8 * g + i;
                f[i] = bf16s(pW2[k * 32 + nt * 16 + c]);
            }
            w2f[nt][kf] = f;
        }
    bf16x8 w3f;
#pragma unroll
    for (int i = 0; i < 8; ++i) w3f[i] = bf16s(pW3[(8 * g + i) * 16 + c]);
    bf16x8 cw1f = z8;
    if (g == 0) {
#pragma unroll
        for (int i = 0; i < 4; ++i) cw1f[i] = bf16s(ctxW1[i * 16 + c]);
        cw1f[4] = bf16s(ctxb1[c]);
    }
    bf16x8 cw2f = z8;
    if (g < 2) {
#pragma unroll
        for (int i = 0; i < 8; ++i) {
            int k = 8 * g + i;
            cw2f[i] = (c < 8) ? bf16s(ctxW2[k * 8 + c]) : (short)0;
        }
    }
    f32x4 b2i[2];
#pragma unroll
    for (int nt = 0; nt < 2; ++nt) {
        float4 t = ((const float4*)pb2)[nt * 4 + g];
        b2i[nt] = (f32x4){t.x, t.y, t.z, t.w};
    }
    float4 t3 = ((const float4*)pb3)[g];
    f32x4 b3i = (f32x4){t3.x, t3.y, t3.z, t3.w};
    f32x4 cb2i = z4;
    float4 cw3v = make_float4(0.f, 0.f, 0.f, 0.f);
    if (g < 2) {
        float4 tb = ((const float4*)ctxb2)[g];
        cb2i = (f32x4){tb.x, tb.y, tb.z, tb.w};
        cw3v = ((const float4*)ctxW3)[g];
    }
    float4 wog = ((const float4*)pWo)[g];

    const int ewave = blockIdx.x * 256 + wid * 64;

    // ---------------- phase 1: per-element components (64-wide) --------------
    {
        const int e = ewave + lane;
        float tpv = tp[e], cv = crit[e], cnv = conn[e], snv = sens[e];
        float bvv = bv[e], dvv = dsv[e], cpv = comp[e], rtv = rt[e], svv = sev[e];
        float threat = fast_sigmoid(3.0f * tpv);
        float impact = (m > 0.0f) ? cv * inv_md : cv;
        float vuln   = svv * 0.1f;
        float invrt  = __builtin_amdgcn_rcpf(rtv + 1e-6f);
        float pbase  = (wt * threat + wi * impact + wv * vuln) * inv_tw;
        uint4 fv;
        fv.x = pk2(bvv, dvv);
        fv.y = pk2(cpv, invrt);
        fv.z = pk2(1.0f, cv);   // [1.0 | crit]
        fv.w = pk2(cnv, snv);   // [conn | sens]
        *(uint4*)(feat + lane * 16) = fv;
        pbf[lane] = pbase;
    }
    // ---------------- phase 2: 4 tiles of 16 elements (ping-pong slabs) ------
    float ovs[4];
#pragma unroll
    for (int t = 0; t < 4; ++t) {
        char* slab = my + 1280 + (t & 1) * 3584;
        char* act1 = slab;
        char* act2 = slab + 2048;
        char* cact = slab + 3072;

        uint4 fr = make_uint4(0u, 0u, 0u, 0u);
        if (g == 0) fr = *(const uint4*)(feat + (t * 16 + c) * 16);
        bf16x8 bctx;
        __builtin_memcpy(&bctx, &fr, sizeof(bctx));
        // ctx L1: 4->16 (+bias via k=4)
        f32x4 cc1 = __builtin_amdgcn_mfma_f32_16x16x32_bf16(cw1f, bctx, z4, 0, 0, 0);
        {
            uint lo = pk2(relu_(cc1[0]), relu_(cc1[1]));
            uint hi = pk2(relu_(cc1[2]), relu_(cc1[3]));
            *(uint2*)(cact + c * 32 + (((g >> 1) ^ (c & 1)) << 4) + 8 * (g & 1)) =
                make_uint2(lo, hi);
        }
        // ctx L2: 16->8
        bf16x8 b2c = z8;
        if (g < 2) b2c = *(const bf16x8*)(cact + c * 32 + ((g ^ (c & 1)) << 4));
        f32x4 cc2 = __builtin_amdgcn_mfma_f32_16x16x32_bf16(cw2f, b2c, cb2i, 0, 0, 0);
        float pc = fmaf(relu_(cc2[0]), cw3v.x, fmaf(relu_(cc2[1]), cw3v.y,
                   fmaf(relu_(cc2[2]), cw3v.z, relu_(cc2[3]) * cw3v.w)));
        pc += __shfl_xor(pc, 16);
        pc += __shfl_xor(pc, 32);
        float ctxr = fast_sigmoid(pc + cb3);
        float base = fmaf(wcn, ctxr, pbf[t * 16 + c]);
        // prop L1 B-frag: [base, crit, conn, sens, 1.0, 0,0,0]
        uint4 pfu = make_uint4(0u, 0u, 0u, 0u);
        if (g == 0) {
            pfu.x = bf16rne(base) | (fr.z & 0xffff0000u);
            pfu.y = fr.w;
            pfu.z = 0x3f80u;
        }
        bf16x8 bp;
        __builtin_memcpy(&bp, &pfu, sizeof(bp));
        // prop L1: 4->64
        f32x4 c1[4];
#pragma unroll
        for (int nt = 0; nt < 4; ++nt)
            c1[nt] = __builtin_amdgcn_mfma_f32_16x16x32_bf16(w1f[nt], bp, z4, 0, 0, 0);
#pragma unroll
        for (int nt = 0; nt < 4; ++nt) {
            uint lo = pk2(relu_(c1[nt][0]), relu_(c1[nt][1]));
            uint hi = pk2(relu_(c1[nt][2]), relu_(c1[nt][3]));
            *(uint2*)(act1 + c * 128 + (((2 * nt + (g >> 1)) ^ (c & 7)) << 4) + 8 * (g & 1)) =
                make_uint2(lo, hi);
        }
        // prop L2: 64->32
        bf16x8 a0 = *(const bf16x8*)(act1 + c * 128 + ((g ^ (c & 7)) << 4));
        bf16x8 a1 = *(const bf16x8*)(act1 + c * 128 + (((4 + g) ^ (c & 7)) << 4));
        f32x4 c2[2];
#pragma unroll
        for (int nt = 0; nt < 2; ++nt) {
            f32x4 acc = __builtin_amdgcn_mfma_f32_16x16x32_bf16(w2f[nt][0], a0, b2i[nt], 0, 0, 0);
            c2[nt] = __builtin_amdgcn_mfma_f32_16x16x32_bf16(w2f[nt][1], a1, acc, 0, 0, 0);
        }
#pragma unroll
        for (int nt = 0; nt < 2; ++nt) {
            uint lo = pk2(relu_(c2[nt][0]), relu_(c2[nt][1]));
            uint hi = pk2(relu_(c2[nt][2]), relu_(c2[nt][3]));
            *(uint2*)(act2 + c * 64 + (((2 * nt + (g >> 1)) ^ (c & 3)) << 4) + 8 * (g & 1)) =
                make_uint2(lo, hi);
        }
        // prop L3: 32->16
        bf16x8 a3 = *(const bf16x8*)(act2 + c * 64 + ((g ^ (c & 3)) << 4));
        f32x4 c3 = __builtin_amdgcn_mfma_f32_16x16x32_bf16(w3f, a3, b3i, 0, 0, 0);
        // output layer 16->1 + sigmoid
        float p = fmaf(relu_(c3[0]), wog.x, fmaf(relu_(c3[1]), wog.y,
                  fmaf(relu_(c3[2]), wog.z, relu_(c3[3]) * wog.w)));
        p += __shfl_xor(p, 16);
        p += __shfl_xor(p, 32);
        ovs[t] = fast_sigmoid(p + pbo0);
    }
    // lane (g,c) stores element ewave + g*16 + c == ewave + lane (coalesced)
    float ov = (g == 0) ? ovs[0] : (g == 1) ? ovs[1] : (g == 2) ? ovs[2] : ovs[3];
    out[ewave + lane] = ov;
}

extern "C" void kernel_launch(void* const* d_in, const int* in_sizes, int n_in,
                              void* d_out, int out_size, void* d_ws, size_t ws_size,
                              hipStream_t stream) {
    const float* tp    = (const float*)d_in[0];
    const float* crit  = (const float*)d_in[1];
    const float* conn  = (const float*)d_in[2];
    const float* sens  = (const float*)d_in[3];
    const float* bv    = (const float*)d_in[4];
    const float* dsv   = (const float*)d_in[5];
    const float* comp  = (const float*)d_in[6];
    const float* rt    = (const float*)d_in[7];
    const float* sev   = (const float*)d_in[8];
    const float* ctxW1 = (const float*)d_in[9];
    const float* ctxb1 = (const float*)d_in[10];
    const float* ctxW2 = (const float*)d_in[11];
    const float* ctxb2 = (const float*)d_in[12];
    const float* ctxW3 = (const float*)d_in[13];
    const float* ctxb3 = (const float*)d_in[14];
    const float* pW1   = (const float*)d_in[15];
    const float* pb1   = (const float*)d_in[16];
    const float* pW2   = (const float*)d_in[17];
    const float* pb2   = (const float*)d_in[18];
    const float* pW3   = (const float*)d_in[19];
    const float* pb3   = (const float*)d_in[20];
    const float* pWo   = (const float*)d_in[21];
    const float* pbo   = (const float*)d_in[22];
    const float* w_t   = (const float*)d_in[23];
    const float* w_i   = (const float*)d_in[24];
    const float* w_v   = (const float*)d_in[25];
    const float* w_c   = (const float*)d_in[26];

    unsigned int* ws_max = (unsigned int*)d_ws;
    float* out = (float*)d_out;

    (void)hipMemsetAsync(ws_max, 0, sizeof(unsigned int), stream);
    crit_max_kernel<<<256, 256, 0, stream>>>(crit, ws_max, TOTAL / 4);
    risk_mfma_kernel<<<BLOCKS, 256, 0, stream>>>(
        tp, crit, conn, sens, bv, dsv, comp, rt, sev,
        ctxW1, ctxb1, ctxW2, ctxb2, ctxW3, ctxb3,
        pW1, pb1, pW2, pb2, pW3, pb3, pWo, pbo,
        w_t, w_i, w_v, w_c, ws_max, out);
}